// Round 3
// baseline (630.569 us; speedup 1.0000x reference)
//
#include <hip/hip_runtime.h>
#include <hip/hip_bf16.h>
#include <math.h>

#define N_NODES 50000
#define N_EDGES 800000
#define NH 4

// ---------------- CSR build ----------------

__global__ void k_hist(const int* __restrict__ dst, int* __restrict__ deg) {
    int i = blockIdx.x * 256 + threadIdx.x;
    if (i < N_EDGES) atomicAdd(&deg[dst[i]], 1);
}

__global__ __launch_bounds__(1024) void k_scan1(const int* __restrict__ deg,
                                                int* __restrict__ offs,
                                                int* __restrict__ bsum) {
    __shared__ int tmp[1024];
    int b = blockIdx.x, t = threadIdx.x;
    int i = b * 1024 + t;
    int v = (i < N_NODES) ? deg[i] : 0;
    tmp[t] = v;
    __syncthreads();
    for (int off = 1; off < 1024; off <<= 1) {
        int add = (t >= off) ? tmp[t - off] : 0;
        __syncthreads();
        tmp[t] += add;
        __syncthreads();
    }
    if (i < N_NODES) offs[i] = tmp[t] - v;
    if (t == 1023) bsum[b] = tmp[t];
}

__global__ void k_scan2(int* __restrict__ bsum, int nb) {
    if (blockIdx.x == 0 && threadIdx.x == 0) {
        int run = 0;
        for (int b = 0; b < nb; ++b) { int v = bsum[b]; bsum[b] = run; run += v; }
    }
}

__global__ __launch_bounds__(1024) void k_scan3(int* __restrict__ offs,
                                                const int* __restrict__ bsum,
                                                int* __restrict__ cursor) {
    int b = blockIdx.x, t = threadIdx.x;
    int i = b * 1024 + t;
    if (i < N_NODES) {
        int o = offs[i] + bsum[b];
        offs[i] = o;
        cursor[i] = o;
    }
    if (b == 0 && t == 0) offs[N_NODES] = N_EDGES;
}

__global__ void k_scatter(const int* __restrict__ src, const int* __restrict__ dst,
                          int* __restrict__ cursor, int* __restrict__ csrc) {
    int i = blockIdx.x * 256 + threadIdx.x;
    if (i < N_EDGES) {
        int p = atomicAdd(&cursor[dst[i]], 1);
        csrc[p] = src[i];
    }
}

// ---------------- tiled GEMM: feat = A @ W ----------------
template <int K, int NOUT, int NP, int BM, int NT>
__global__ __launch_bounds__(NT) void gemm_tiled(const float* __restrict__ A,
                                                 const float* __restrict__ W,
                                                 float* __restrict__ feat) {
    constexpr int BK = 32;
    constexpr int NSTRIP = NP / 8;
    __shared__ float lds_a[BK][BM + 4];
    __shared__ float lds_b[BK][NP];
    int tid = threadIdx.x;
    int rs = tid / NSTRIP, cs = tid % NSTRIP;
    int row0 = rs * 4, col0 = cs * 8;
    int m0 = blockIdx.x * BM;
    float acc[4][8];
#pragma unroll
    for (int i = 0; i < 4; ++i)
#pragma unroll
        for (int j = 0; j < 8; ++j) acc[i][j] = 0.f;

    for (int kb = 0; kb < K; kb += BK) {
        for (int idx = tid; idx < BM * (BK / 4); idx += NT) {
            int r = idx >> 3;
            int c4 = idx & 7;
            int gr = m0 + r;
            float4 v = make_float4(0.f, 0.f, 0.f, 0.f);
            if (gr < N_NODES)
                v = *reinterpret_cast<const float4*>(A + (size_t)gr * K + kb + c4 * 4);
            lds_a[c4 * 4 + 0][r] = v.x;
            lds_a[c4 * 4 + 1][r] = v.y;
            lds_a[c4 * 4 + 2][r] = v.z;
            lds_a[c4 * 4 + 3][r] = v.w;
        }
        constexpr int NV4 = NOUT / 4;
        for (int idx = tid; idx < BK * NV4; idx += NT) {
            int r = idx / NV4, c = idx % NV4;
            float4 v = *reinterpret_cast<const float4*>(W + (size_t)(kb + r) * NOUT + c * 4);
            *reinterpret_cast<float4*>(&lds_b[r][c * 4]) = v;
        }
        __syncthreads();
#pragma unroll
        for (int kk = 0; kk < BK; ++kk) {
            float4 a = *reinterpret_cast<const float4*>(&lds_a[kk][row0]);
            float4 b0 = *reinterpret_cast<const float4*>(&lds_b[kk][col0]);
            float4 b1 = *reinterpret_cast<const float4*>(&lds_b[kk][col0 + 4]);
            float av[4] = {a.x, a.y, a.z, a.w};
            float bv[8] = {b0.x, b0.y, b0.z, b0.w, b1.x, b1.y, b1.z, b1.w};
#pragma unroll
            for (int i = 0; i < 4; ++i)
#pragma unroll
                for (int j = 0; j < 8; ++j) acc[i][j] = fmaf(av[i], bv[j], acc[i][j]);
        }
        __syncthreads();
    }
#pragma unroll
    for (int i = 0; i < 4; ++i) {
        int n = m0 + row0 + i;
        if (n >= N_NODES) break;
        float4 v0 = make_float4(acc[i][0], acc[i][1], acc[i][2], acc[i][3]);
        float4 v1 = make_float4(acc[i][4], acc[i][5], acc[i][6], acc[i][7]);
        if (col0 + 4 <= NOUT)
            *reinterpret_cast<float4*>(feat + (size_t)n * NOUT + col0) = v0;
        if (col0 + 8 <= NOUT)
            *reinterpret_cast<float4*>(feat + (size_t)n * NOUT + col0 + 4) = v1;
    }
}

// ---------------- attention dots ----------------
template <int NOUT, int DH>
__global__ __launch_bounds__(256) void attn_dots(const float* __restrict__ feat,
                                                 const float* __restrict__ al,
                                                 const float* __restrict__ ar,
                                                 float* __restrict__ el,
                                                 float* __restrict__ er) {
    int wave = threadIdx.x >> 6, lane = threadIdx.x & 63;
    int n = blockIdx.x * 4 + wave;
    int h = lane >> 4, t = lane & 15;
    const float* f = feat + (size_t)n * NOUT + h * DH;
    const float* alh = al + h * DH;
    const float* arh = ar + h * DH;
    float sl = 0.f, sr = 0.f;
#pragma unroll
    for (int d0 = 0; d0 < DH; d0 += 16) {
        int d = d0 + t;
        if (d < DH) {
            float fv = f[d];
            sl = fmaf(fv, alh[d], sl);
            sr = fmaf(fv, arh[d], sr);
        }
    }
#pragma unroll
    for (int o = 1; o < 16; o <<= 1) {
        sl += __shfl_xor(sl, o);
        sr += __shfl_xor(sr, o);
    }
    if (t == 0) { el[n * NH + h] = sl; er[n * NH + h] = sr; }
}

// ---------------- per-node segment softmax -> normalized alpha[E][4] ----------------
__device__ __forceinline__ float wred_max(float v) {
#pragma unroll
    for (int o = 32; o > 0; o >>= 1) v = fmaxf(v, __shfl_xor(v, o));
    return v;
}
__device__ __forceinline__ float wred_sum(float v) {
#pragma unroll
    for (int o = 32; o > 0; o >>= 1) v += __shfl_xor(v, o);
    return v;
}

__global__ __launch_bounds__(256) void softmax_alpha(const float* __restrict__ el,
                                                     const float* __restrict__ er,
                                                     const int* __restrict__ offs,
                                                     const int* __restrict__ csrc,
                                                     float* __restrict__ alpha) {
    const float NEG = -__builtin_inff();
    int wave = threadIdx.x >> 6, lane = threadIdx.x & 63;
    int n = blockIdx.x * 4 + wave;
    int i0 = offs[n], i1 = offs[n + 1];
    if (i0 >= i1) return;
    float4 erv = *reinterpret_cast<const float4*>(er + (size_t)n * NH);

    if (i1 - i0 <= 64) {
        // fast path: one chunk, keep e in registers
        int i = i0 + lane;
        bool act = i < i1;
        int src = act ? csrc[i] : 0;
        float4 elv = make_float4(0.f, 0.f, 0.f, 0.f);
        if (act) elv = *reinterpret_cast<const float4*>(el + (size_t)src * NH);
        float e0 = elv.x + erv.x; e0 = e0 >= 0.f ? e0 : 0.2f * e0;
        float e1 = elv.y + erv.y; e1 = e1 >= 0.f ? e1 : 0.2f * e1;
        float e2 = elv.z + erv.z; e2 = e2 >= 0.f ? e2 : 0.2f * e2;
        float e3 = elv.w + erv.w; e3 = e3 >= 0.f ? e3 : 0.2f * e3;
        if (!act) { e0 = NEG; e1 = NEG; e2 = NEG; e3 = NEG; }
        float m0 = wred_max(e0), m1 = wred_max(e1), m2 = wred_max(e2), m3 = wred_max(e3);
        float p0 = act ? __expf(e0 - m0) : 0.f;
        float p1 = act ? __expf(e1 - m1) : 0.f;
        float p2 = act ? __expf(e2 - m2) : 0.f;
        float p3 = act ? __expf(e3 - m3) : 0.f;
        float s0 = wred_sum(p0), s1 = wred_sum(p1), s2 = wred_sum(p2), s3 = wred_sum(p3);
        if (act) {
            float4 a = make_float4(p0 / s0, p1 / s1, p2 / s2, p3 / s3);
            *reinterpret_cast<float4*>(alpha + (size_t)i * NH) = a;
        }
        return;
    }

    // general path (deg > 64): online stats, then rescale pass
    float m0 = NEG, m1 = NEG, m2 = NEG, m3 = NEG;
    float s0 = 0.f, s1 = 0.f, s2 = 0.f, s3 = 0.f;
    for (int base = i0; base < i1; base += 64) {
        int i = base + lane;
        bool act = i < i1;
        int src = act ? csrc[i] : 0;
        float4 elv = make_float4(0.f, 0.f, 0.f, 0.f);
        if (act) elv = *reinterpret_cast<const float4*>(el + (size_t)src * NH);
        float e0 = elv.x + erv.x; e0 = e0 >= 0.f ? e0 : 0.2f * e0;
        float e1 = elv.y + erv.y; e1 = e1 >= 0.f ? e1 : 0.2f * e1;
        float e2 = elv.z + erv.z; e2 = e2 >= 0.f ? e2 : 0.2f * e2;
        float e3 = elv.w + erv.w; e3 = e3 >= 0.f ? e3 : 0.2f * e3;
        if (!act) { e0 = NEG; e1 = NEG; e2 = NEG; e3 = NEG; }
        float c0 = wred_max(e0), c1 = wred_max(e1), c2 = wred_max(e2), c3 = wred_max(e3);
        float nm0 = fmaxf(m0, c0), nm1 = fmaxf(m1, c1), nm2 = fmaxf(m2, c2), nm3 = fmaxf(m3, c3);
        float p0 = act ? __expf(e0 - nm0) : 0.f;
        float p1 = act ? __expf(e1 - nm1) : 0.f;
        float p2 = act ? __expf(e2 - nm2) : 0.f;
        float p3 = act ? __expf(e3 - nm3) : 0.f;
        float S0 = wred_sum(p0), S1 = wred_sum(p1), S2 = wred_sum(p2), S3 = wred_sum(p3);
        s0 = s0 * __expf(m0 - nm0) + S0; m0 = nm0;
        s1 = s1 * __expf(m1 - nm1) + S1; m1 = nm1;
        s2 = s2 * __expf(m2 - nm2) + S2; m2 = nm2;
        s3 = s3 * __expf(m3 - nm3) + S3; m3 = nm3;
    }
    float v0 = 1.f / s0, v1 = 1.f / s1, v2 = 1.f / s2, v3 = 1.f / s3;
    for (int base = i0; base < i1; base += 64) {
        int i = base + lane;
        bool act = i < i1;
        int src = act ? csrc[i] : 0;
        float4 elv = make_float4(0.f, 0.f, 0.f, 0.f);
        if (act) elv = *reinterpret_cast<const float4*>(el + (size_t)src * NH);
        float e0 = elv.x + erv.x; e0 = e0 >= 0.f ? e0 : 0.2f * e0;
        float e1 = elv.y + erv.y; e1 = e1 >= 0.f ? e1 : 0.2f * e1;
        float e2 = elv.z + erv.z; e2 = e2 >= 0.f ? e2 : 0.2f * e2;
        float e3 = elv.w + erv.w; e3 = e3 >= 0.f ? e3 : 0.2f * e3;
        if (act) {
            float4 a = make_float4(__expf(e0 - m0) * v0, __expf(e1 - m1) * v1,
                                   __expf(e2 - m2) * v2, __expf(e3 - m3) * v3);
            *reinterpret_cast<float4*>(alpha + (size_t)i * NH) = a;
        }
    }
}

// ---------------- aggregation, layers 1-2 (NOUT=128): pure weighted gather ----
__global__ __launch_bounds__(256) void gat_agg128(const float* __restrict__ feat,
                                                  const float* __restrict__ alpha,
                                                  const int* __restrict__ offs,
                                                  const int* __restrict__ csrc,
                                                  float* __restrict__ out) {
    int wave = threadIdx.x >> 6;
    int lane = threadIdx.x & 63;
    int n = blockIdx.x * 4 + wave;
    int h = lane >> 4;
    int i0 = offs[n], i1 = offs[n + 1];
    float ax = 0.f, ay = 0.f;
    for (int i = i0; i < i1; ++i) {
        int src = csrc[i];
        float a = alpha[(size_t)i * NH + h];
        float2 v = *reinterpret_cast<const float2*>(feat + (size_t)src * 128 + 2 * lane);
        ax = fmaf(a, v.x, ax);
        ay = fmaf(a, v.y, ay);
    }
    float ox = ax > 0.f ? ax : expm1f(ax);
    float oy = ay > 0.f ? ay : expm1f(ay);
    *reinterpret_cast<float2*>(out + (size_t)n * 128 + 2 * lane) = make_float2(ox, oy);
}

// ---------------- aggregation, layer 3 (NOUT=188) + mean + log_softmax ----
__global__ __launch_bounds__(256) void gat_agg_final(const float* __restrict__ feat,
                                                     const float* __restrict__ alpha,
                                                     const int* __restrict__ offs,
                                                     const int* __restrict__ csrc,
                                                     float* __restrict__ out) {
    __shared__ float lds[4][188];
    int wave = threadIdx.x >> 6;
    int lane = threadIdx.x & 63;
    int n = blockIdx.x * 4 + wave;
    bool b0 = lane >= 47;
    bool b1 = lane >= 30;
    bool b2 = lane >= 13;
    int i0 = offs[n], i1 = offs[n + 1];
    float a0 = 0.f, a1 = 0.f, a2 = 0.f;
    for (int i = i0; i < i1; ++i) {
        int src = csrc[i];
        float4 av = *reinterpret_cast<const float4*>(alpha + (size_t)i * NH);
        const float* fr = feat + (size_t)src * 188;
        float v0 = fr[lane];
        float v1 = fr[lane + 64];
        float v2 = (lane < 60) ? fr[lane + 128] : 0.f;
        float w0 = b0 ? av.y : av.x;
        float w1 = b1 ? av.z : av.y;
        float w2 = b2 ? av.w : av.z;
        a0 = fmaf(w0, v0, a0);
        a1 = fmaf(w1, v1, a1);
        a2 = fmaf(w2, v2, a2);
    }
    lds[wave][lane] = a0;
    lds[wave][lane + 64] = a1;
    if (lane < 60) lds[wave][lane + 128] = a2;
    __syncthreads();
    float u = (lane < 47)
                  ? 0.25f * (lds[wave][lane] + lds[wave][47 + lane] +
                             lds[wave][94 + lane] + lds[wave][141 + lane])
                  : -__builtin_inff();
    float mx = u;
#pragma unroll
    for (int o = 32; o > 0; o >>= 1) mx = fmaxf(mx, __shfl_xor(mx, o));
    float ex = (lane < 47) ? __expf(u - mx) : 0.f;
    float sm = ex;
#pragma unroll
    for (int o = 32; o > 0; o >>= 1) sm += __shfl_xor(sm, o);
    if (lane < 47) out[(size_t)n * 47 + lane] = u - mx - logf(sm);
}

// ---------------- launch ----------------

extern "C" void kernel_launch(void* const* d_in, const int* in_sizes, int n_in,
                              void* d_out, int out_size, void* d_ws, size_t ws_size,
                              hipStream_t stream) {
    const float* x = (const float*)d_in[0];
    const int* src = (const int*)d_in[1];
    const int* dst = (const int*)d_in[2];
    const float* W1 = (const float*)d_in[3];
    const float* al1 = (const float*)d_in[4];
    const float* ar1 = (const float*)d_in[5];
    const float* W2 = (const float*)d_in[6];
    const float* al2 = (const float*)d_in[7];
    const float* ar2 = (const float*)d_in[8];
    const float* W3 = (const float*)d_in[9];
    const float* al3 = (const float*)d_in[10];
    const float* ar3 = (const float*)d_in[11];
    float* out = (float*)d_out;

    char* p = (char*)d_ws;
    auto alloc = [&](size_t bytes) {
        char* r = p;
        p += (bytes + 255) & ~(size_t)255;
        return r;
    };
    float* bufA = (float*)alloc((size_t)N_NODES * 128 * 4);
    float* bufB = (float*)alloc((size_t)N_NODES * 188 * 4);
    float* bufC = (float*)alloc((size_t)N_NODES * 128 * 4);
    float* el = (float*)alloc((size_t)N_NODES * NH * 4);
    float* er = (float*)alloc((size_t)N_NODES * NH * 4);
    float* alpha = (float*)alloc((size_t)N_EDGES * NH * 4);
    int* deg = (int*)alloc((size_t)N_NODES * 4);
    int* offs = (int*)alloc((size_t)(N_NODES + 1) * 4);
    int* cursor = (int*)alloc((size_t)N_NODES * 4);
    int* bsum = (int*)alloc(64 * 4);
    int* csrc = (int*)alloc((size_t)N_EDGES * 4);

    // CSR by dst
    hipMemsetAsync(deg, 0, (size_t)N_NODES * 4, stream);
    k_hist<<<(N_EDGES + 255) / 256, 256, 0, stream>>>(dst, deg);
    k_scan1<<<49, 1024, 0, stream>>>(deg, offs, bsum);
    k_scan2<<<1, 64, 0, stream>>>(bsum, 49);
    k_scan3<<<49, 1024, 0, stream>>>(offs, bsum, cursor);
    k_scatter<<<(N_EDGES + 255) / 256, 256, 0, stream>>>(src, dst, cursor, csrc);

    // layer 1
    gemm_tiled<256, 128, 128, 64, 256><<<(N_NODES + 63) / 64, 256, 0, stream>>>(x, W1, bufB);
    attn_dots<128, 32><<<N_NODES / 4, 256, 0, stream>>>(bufB, al1, ar1, el, er);
    softmax_alpha<<<N_NODES / 4, 256, 0, stream>>>(el, er, offs, csrc, alpha);
    gat_agg128<<<N_NODES / 4, 256, 0, stream>>>(bufB, alpha, offs, csrc, bufA);
    // layer 2
    gemm_tiled<128, 128, 128, 64, 256><<<(N_NODES + 63) / 64, 256, 0, stream>>>(bufA, W2, bufB);
    attn_dots<128, 32><<<N_NODES / 4, 256, 0, stream>>>(bufB, al2, ar2, el, er);
    softmax_alpha<<<N_NODES / 4, 256, 0, stream>>>(el, er, offs, csrc, alpha);
    gat_agg128<<<N_NODES / 4, 256, 0, stream>>>(bufB, alpha, offs, csrc, bufC);
    // layer 3
    gemm_tiled<128, 188, 192, 32, 192><<<(N_NODES + 31) / 32, 192, 0, stream>>>(bufC, W3, bufB);
    attn_dots<188, 47><<<N_NODES / 4, 256, 0, stream>>>(bufB, al3, ar3, el, er);
    softmax_alpha<<<N_NODES / 4, 256, 0, stream>>>(el, er, offs, csrc, alpha);
    gat_agg_final<<<N_NODES / 4, 256, 0, stream>>>(bufB, alpha, offs, csrc, out);
}

// Round 4
// 510.814 us; speedup vs baseline: 1.2344x; 1.2344x over previous
//
#include <hip/hip_runtime.h>
#include <hip/hip_bf16.h>
#include <math.h>
#include <string.h>

#define N_NODES 50000
#define N_EDGES 800000
#define NH 4

typedef unsigned int u32;
typedef unsigned short u16;

__device__ __forceinline__ u32 pack_bf2(float a, float b) {
    __hip_bfloat162 h2 = __float22bfloat162_rn(make_float2(a, b));
    u32 r;
    memcpy(&r, &h2, 4);
    return r;
}
__device__ __forceinline__ float2 bf2_to_f2(u32 u) {
    return make_float2(__uint_as_float(u << 16), __uint_as_float(u & 0xffff0000u));
}

// ---------------- CSR build ----------------

__global__ void k_hist(const int* __restrict__ dst, int* __restrict__ deg) {
    int i = blockIdx.x * 256 + threadIdx.x;
    if (i < N_EDGES) atomicAdd(&deg[dst[i]], 1);
}

__global__ __launch_bounds__(1024) void k_scan1(const int* __restrict__ deg,
                                                int* __restrict__ offs,
                                                int* __restrict__ bsum) {
    __shared__ int tmp[1024];
    int b = blockIdx.x, t = threadIdx.x;
    int i = b * 1024 + t;
    int v = (i < N_NODES) ? deg[i] : 0;
    tmp[t] = v;
    __syncthreads();
    for (int off = 1; off < 1024; off <<= 1) {
        int add = (t >= off) ? tmp[t - off] : 0;
        __syncthreads();
        tmp[t] += add;
        __syncthreads();
    }
    if (i < N_NODES) offs[i] = tmp[t] - v;
    if (t == 1023) bsum[b] = tmp[t];
}

__global__ void k_scan2(int* __restrict__ bsum, int nb) {
    if (blockIdx.x == 0 && threadIdx.x == 0) {
        int run = 0;
        for (int b = 0; b < nb; ++b) { int v = bsum[b]; bsum[b] = run; run += v; }
    }
}

__global__ __launch_bounds__(1024) void k_scan3(int* __restrict__ offs,
                                                const int* __restrict__ bsum,
                                                int* __restrict__ cursor) {
    int b = blockIdx.x, t = threadIdx.x;
    int i = b * 1024 + t;
    if (i < N_NODES) {
        int o = offs[i] + bsum[b];
        offs[i] = o;
        cursor[i] = o;
    }
    if (b == 0 && t == 0) offs[N_NODES] = N_EDGES;
}

__global__ void k_scatter(const int* __restrict__ src, const int* __restrict__ dst,
                          int* __restrict__ cursor, int* __restrict__ csrc) {
    int i = blockIdx.x * 256 + threadIdx.x;
    if (i < N_EDGES) {
        int p = atomicAdd(&cursor[dst[i]], 1);
        csrc[p] = src[i];
    }
}

// ---------------- tiled GEMM: feat(bf16) = A(f32) @ W(f32) ----------------
template <int K, int NOUT, int NP, int BM, int NT, int OSTRIDE>
__global__ __launch_bounds__(NT) void gemm_tiled(const float* __restrict__ A,
                                                 const float* __restrict__ W,
                                                 u16* __restrict__ feat) {
    constexpr int BK = 32;
    constexpr int NSTRIP = NP / 8;
    __shared__ float lds_a[BK][BM + 4];
    __shared__ float lds_b[BK][NP];
    int tid = threadIdx.x;
    int rs = tid / NSTRIP, cs = tid % NSTRIP;
    int row0 = rs * 4, col0 = cs * 8;
    int m0 = blockIdx.x * BM;
    float acc[4][8];
#pragma unroll
    for (int i = 0; i < 4; ++i)
#pragma unroll
        for (int j = 0; j < 8; ++j) acc[i][j] = 0.f;

    for (int kb = 0; kb < K; kb += BK) {
        for (int idx = tid; idx < BM * (BK / 4); idx += NT) {
            int r = idx >> 3;
            int c4 = idx & 7;
            int gr = m0 + r;
            float4 v = make_float4(0.f, 0.f, 0.f, 0.f);
            if (gr < N_NODES)
                v = *reinterpret_cast<const float4*>(A + (size_t)gr * K + kb + c4 * 4);
            lds_a[c4 * 4 + 0][r] = v.x;
            lds_a[c4 * 4 + 1][r] = v.y;
            lds_a[c4 * 4 + 2][r] = v.z;
            lds_a[c4 * 4 + 3][r] = v.w;
        }
        constexpr int NV4 = NOUT / 4;
        for (int idx = tid; idx < BK * NV4; idx += NT) {
            int r = idx / NV4, c = idx % NV4;
            float4 v = *reinterpret_cast<const float4*>(W + (size_t)(kb + r) * NOUT + c * 4);
            *reinterpret_cast<float4*>(&lds_b[r][c * 4]) = v;
        }
        __syncthreads();
#pragma unroll
        for (int kk = 0; kk < BK; ++kk) {
            float4 a = *reinterpret_cast<const float4*>(&lds_a[kk][row0]);
            float4 b0 = *reinterpret_cast<const float4*>(&lds_b[kk][col0]);
            float4 b1 = *reinterpret_cast<const float4*>(&lds_b[kk][col0 + 4]);
            float av[4] = {a.x, a.y, a.z, a.w};
            float bv[8] = {b0.x, b0.y, b0.z, b0.w, b1.x, b1.y, b1.z, b1.w};
#pragma unroll
            for (int i = 0; i < 4; ++i)
#pragma unroll
                for (int j = 0; j < 8; ++j) acc[i][j] = fmaf(av[i], bv[j], acc[i][j]);
        }
        __syncthreads();
    }
#pragma unroll
    for (int i = 0; i < 4; ++i) {
        int n = m0 + row0 + i;
        if (n >= N_NODES) break;
        u32 p0 = pack_bf2(acc[i][0], acc[i][1]);
        u32 p1 = pack_bf2(acc[i][2], acc[i][3]);
        u32 p2 = pack_bf2(acc[i][4], acc[i][5]);
        u32 p3 = pack_bf2(acc[i][6], acc[i][7]);
        u16* dstp = feat + (size_t)n * OSTRIDE + col0;
        if (col0 + 8 <= NOUT) {
            *reinterpret_cast<uint4*>(dstp) = make_uint4(p0, p1, p2, p3);
        } else {
            *reinterpret_cast<uint2*>(dstp) = make_uint2(p0, p1);  // cols 184..187
        }
    }
}

// ---------------- attention dots (bf16 feat) ----------------
template <int DH, int STRIDE>
__global__ __launch_bounds__(256) void attn_dots(const u16* __restrict__ feat,
                                                 const float* __restrict__ al,
                                                 const float* __restrict__ ar,
                                                 float* __restrict__ el,
                                                 float* __restrict__ er) {
    int wave = threadIdx.x >> 6, lane = threadIdx.x & 63;
    int n = blockIdx.x * 4 + wave;
    int h = lane >> 4, t = lane & 15;
    const u16* f = feat + (size_t)n * STRIDE + h * DH;
    const float* alh = al + h * DH;
    const float* arh = ar + h * DH;
    float sl = 0.f, sr = 0.f;
#pragma unroll
    for (int d0 = 0; d0 < DH; d0 += 16) {
        int d = d0 + t;
        if (d < DH) {
            float fv = __uint_as_float(((u32)f[d]) << 16);
            sl = fmaf(fv, alh[d], sl);
            sr = fmaf(fv, arh[d], sr);
        }
    }
#pragma unroll
    for (int o = 1; o < 16; o <<= 1) {
        sl += __shfl_xor(sl, o);
        sr += __shfl_xor(sr, o);
    }
    if (t == 0) { el[n * NH + h] = sl; er[n * NH + h] = sr; }
}

// ---------------- per-node segment softmax -> normalized alpha[E][4] ----------------
__device__ __forceinline__ float wred_max(float v) {
#pragma unroll
    for (int o = 32; o > 0; o >>= 1) v = fmaxf(v, __shfl_xor(v, o));
    return v;
}
__device__ __forceinline__ float wred_sum(float v) {
#pragma unroll
    for (int o = 32; o > 0; o >>= 1) v += __shfl_xor(v, o);
    return v;
}

__global__ __launch_bounds__(256) void softmax_alpha(const float* __restrict__ el,
                                                     const float* __restrict__ er,
                                                     const int* __restrict__ offs,
                                                     const int* __restrict__ csrc,
                                                     float* __restrict__ alpha) {
    const float NEG = -__builtin_inff();
    int wave = threadIdx.x >> 6, lane = threadIdx.x & 63;
    int n = blockIdx.x * 4 + wave;
    int i0 = offs[n], i1 = offs[n + 1];
    if (i0 >= i1) return;
    float4 erv = *reinterpret_cast<const float4*>(er + (size_t)n * NH);

    if (i1 - i0 <= 64) {
        int i = i0 + lane;
        bool act = i < i1;
        int src = act ? csrc[i] : 0;
        float4 elv = make_float4(0.f, 0.f, 0.f, 0.f);
        if (act) elv = *reinterpret_cast<const float4*>(el + (size_t)src * NH);
        float e0 = elv.x + erv.x; e0 = e0 >= 0.f ? e0 : 0.2f * e0;
        float e1 = elv.y + erv.y; e1 = e1 >= 0.f ? e1 : 0.2f * e1;
        float e2 = elv.z + erv.z; e2 = e2 >= 0.f ? e2 : 0.2f * e2;
        float e3 = elv.w + erv.w; e3 = e3 >= 0.f ? e3 : 0.2f * e3;
        if (!act) { e0 = NEG; e1 = NEG; e2 = NEG; e3 = NEG; }
        float m0 = wred_max(e0), m1 = wred_max(e1), m2 = wred_max(e2), m3 = wred_max(e3);
        float p0 = act ? __expf(e0 - m0) : 0.f;
        float p1 = act ? __expf(e1 - m1) : 0.f;
        float p2 = act ? __expf(e2 - m2) : 0.f;
        float p3 = act ? __expf(e3 - m3) : 0.f;
        float s0 = wred_sum(p0), s1 = wred_sum(p1), s2 = wred_sum(p2), s3 = wred_sum(p3);
        if (act) {
            float4 a = make_float4(p0 / s0, p1 / s1, p2 / s2, p3 / s3);
            *reinterpret_cast<float4*>(alpha + (size_t)i * NH) = a;
        }
        return;
    }

    float m0 = NEG, m1 = NEG, m2 = NEG, m3 = NEG;
    float s0 = 0.f, s1 = 0.f, s2 = 0.f, s3 = 0.f;
    for (int base = i0; base < i1; base += 64) {
        int i = base + lane;
        bool act = i < i1;
        int src = act ? csrc[i] : 0;
        float4 elv = make_float4(0.f, 0.f, 0.f, 0.f);
        if (act) elv = *reinterpret_cast<const float4*>(el + (size_t)src * NH);
        float e0 = elv.x + erv.x; e0 = e0 >= 0.f ? e0 : 0.2f * e0;
        float e1 = elv.y + erv.y; e1 = e1 >= 0.f ? e1 : 0.2f * e1;
        float e2 = elv.z + erv.z; e2 = e2 >= 0.f ? e2 : 0.2f * e2;
        float e3 = elv.w + erv.w; e3 = e3 >= 0.f ? e3 : 0.2f * e3;
        if (!act) { e0 = NEG; e1 = NEG; e2 = NEG; e3 = NEG; }
        float c0 = wred_max(e0), c1 = wred_max(e1), c2 = wred_max(e2), c3 = wred_max(e3);
        float nm0 = fmaxf(m0, c0), nm1 = fmaxf(m1, c1), nm2 = fmaxf(m2, c2), nm3 = fmaxf(m3, c3);
        float p0 = act ? __expf(e0 - nm0) : 0.f;
        float p1 = act ? __expf(e1 - nm1) : 0.f;
        float p2 = act ? __expf(e2 - nm2) : 0.f;
        float p3 = act ? __expf(e3 - nm3) : 0.f;
        float S0 = wred_sum(p0), S1 = wred_sum(p1), S2 = wred_sum(p2), S3 = wred_sum(p3);
        s0 = s0 * __expf(m0 - nm0) + S0; m0 = nm0;
        s1 = s1 * __expf(m1 - nm1) + S1; m1 = nm1;
        s2 = s2 * __expf(m2 - nm2) + S2; m2 = nm2;
        s3 = s3 * __expf(m3 - nm3) + S3; m3 = nm3;
    }
    float v0 = 1.f / s0, v1 = 1.f / s1, v2 = 1.f / s2, v3 = 1.f / s3;
    for (int base = i0; base < i1; base += 64) {
        int i = base + lane;
        bool act = i < i1;
        int src = act ? csrc[i] : 0;
        float4 elv = make_float4(0.f, 0.f, 0.f, 0.f);
        if (act) elv = *reinterpret_cast<const float4*>(el + (size_t)src * NH);
        float e0 = elv.x + erv.x; e0 = e0 >= 0.f ? e0 : 0.2f * e0;
        float e1 = elv.y + erv.y; e1 = e1 >= 0.f ? e1 : 0.2f * e1;
        float e2 = elv.z + erv.z; e2 = e2 >= 0.f ? e2 : 0.2f * e2;
        float e3 = elv.w + erv.w; e3 = e3 >= 0.f ? e3 : 0.2f * e3;
        if (act) {
            float4 a = make_float4(__expf(e0 - m0) * v0, __expf(e1 - m1) * v1,
                                   __expf(e2 - m2) * v2, __expf(e3 - m3) * v3);
            *reinterpret_cast<float4*>(alpha + (size_t)i * NH) = a;
        }
    }
}

// ---------------- aggregation, layers 1-2 (128 cols, bf16 feat) ----------------
__global__ __launch_bounds__(256) void gat_agg128(const u16* __restrict__ feat,
                                                  const float* __restrict__ alpha,
                                                  const int* __restrict__ offs,
                                                  const int* __restrict__ csrc,
                                                  float* __restrict__ out) {
    int wave = threadIdx.x >> 6;
    int lane = threadIdx.x & 63;
    int n = blockIdx.x * 4 + wave;
    int h = lane >> 4;
    int i0 = offs[n], i1 = offs[n + 1];
    float ax = 0.f, ay = 0.f;
    int i = i0;
    // 4-deep static unroll: 4 independent row-gathers in flight
    for (; i + 4 <= i1; i += 4) {
        int s0 = csrc[i], s1 = csrc[i + 1], s2 = csrc[i + 2], s3 = csrc[i + 3];
        float a0 = alpha[(size_t)(i + 0) * NH + h];
        float a1 = alpha[(size_t)(i + 1) * NH + h];
        float a2 = alpha[(size_t)(i + 2) * NH + h];
        float a3 = alpha[(size_t)(i + 3) * NH + h];
        u32 u0 = *reinterpret_cast<const u32*>(feat + (size_t)s0 * 128 + 2 * lane);
        u32 u1 = *reinterpret_cast<const u32*>(feat + (size_t)s1 * 128 + 2 * lane);
        u32 u2 = *reinterpret_cast<const u32*>(feat + (size_t)s2 * 128 + 2 * lane);
        u32 u3 = *reinterpret_cast<const u32*>(feat + (size_t)s3 * 128 + 2 * lane);
        float2 v;
        v = bf2_to_f2(u0); ax = fmaf(a0, v.x, ax); ay = fmaf(a0, v.y, ay);
        v = bf2_to_f2(u1); ax = fmaf(a1, v.x, ax); ay = fmaf(a1, v.y, ay);
        v = bf2_to_f2(u2); ax = fmaf(a2, v.x, ax); ay = fmaf(a2, v.y, ay);
        v = bf2_to_f2(u3); ax = fmaf(a3, v.x, ax); ay = fmaf(a3, v.y, ay);
    }
    for (; i < i1; ++i) {
        int s = csrc[i];
        float a = alpha[(size_t)i * NH + h];
        u32 u = *reinterpret_cast<const u32*>(feat + (size_t)s * 128 + 2 * lane);
        float2 v = bf2_to_f2(u);
        ax = fmaf(a, v.x, ax); ay = fmaf(a, v.y, ay);
    }
    float ox = ax > 0.f ? ax : expm1f(ax);
    float oy = ay > 0.f ? ay : expm1f(ay);
    *reinterpret_cast<float2*>(out + (size_t)n * 128 + 2 * lane) = make_float2(ox, oy);
}

// ---------------- aggregation, layer 3 (188 cols, stride 192) + mean + log_softmax ----
__global__ __launch_bounds__(256) void gat_agg_final(const u16* __restrict__ feat,
                                                     const float* __restrict__ alpha,
                                                     const int* __restrict__ offs,
                                                     const int* __restrict__ csrc,
                                                     float* __restrict__ out) {
    __shared__ float lds[4][188];
    int wave = threadIdx.x >> 6;
    int lane = threadIdx.x & 63;
    int n = blockIdx.x * 4 + wave;
    // lane covers elems 2*lane, 2*lane+1 (0..127) and, for lane<30, 128+2*lane, 129+2*lane
    int e0 = 2 * lane;
    int h00 = e0 / 47;
    int h01 = (e0 + 1) / 47;
    bool act30 = lane < 30;
    int h10 = act30 ? (128 + e0) / 47 : 0;
    int h11 = act30 ? (129 + e0) / 47 : 0;
    int i0 = offs[n], i1 = offs[n + 1];
    float a00 = 0.f, a01 = 0.f, a10 = 0.f, a11 = 0.f;
    int i = i0;
    // 2-deep unroll: 4 row-loads in flight
    for (; i + 2 <= i1; i += 2) {
        int sA = csrc[i], sB = csrc[i + 1];
        const float* apA = alpha + (size_t)i * NH;
        const float* apB = alpha + (size_t)(i + 1) * NH;
        float wA00 = apA[h00], wA01 = apA[h01], wA10 = apA[h10], wA11 = apA[h11];
        float wB00 = apB[h00], wB01 = apB[h01], wB10 = apB[h10], wB11 = apB[h11];
        const u16* rA = feat + (size_t)sA * 192;
        const u16* rB = feat + (size_t)sB * 192;
        u32 uA0 = *reinterpret_cast<const u32*>(rA + e0);
        u32 uB0 = *reinterpret_cast<const u32*>(rB + e0);
        u32 uA1 = act30 ? *reinterpret_cast<const u32*>(rA + 128 + e0) : 0u;
        u32 uB1 = act30 ? *reinterpret_cast<const u32*>(rB + 128 + e0) : 0u;
        float2 v;
        v = bf2_to_f2(uA0); a00 = fmaf(wA00, v.x, a00); a01 = fmaf(wA01, v.y, a01);
        v = bf2_to_f2(uA1); a10 = fmaf(wA10, v.x, a10); a11 = fmaf(wA11, v.y, a11);
        v = bf2_to_f2(uB0); a00 = fmaf(wB00, v.x, a00); a01 = fmaf(wB01, v.y, a01);
        v = bf2_to_f2(uB1); a10 = fmaf(wB10, v.x, a10); a11 = fmaf(wB11, v.y, a11);
    }
    for (; i < i1; ++i) {
        int s = csrc[i];
        const float* ap = alpha + (size_t)i * NH;
        float w00 = ap[h00], w01 = ap[h01], w10 = ap[h10], w11 = ap[h11];
        const u16* r = feat + (size_t)s * 192;
        u32 u0 = *reinterpret_cast<const u32*>(r + e0);
        u32 u1 = act30 ? *reinterpret_cast<const u32*>(r + 128 + e0) : 0u;
        float2 v;
        v = bf2_to_f2(u0); a00 = fmaf(w00, v.x, a00); a01 = fmaf(w01, v.y, a01);
        v = bf2_to_f2(u1); a10 = fmaf(w10, v.x, a10); a11 = fmaf(w11, v.y, a11);
    }
    lds[wave][e0] = a00;
    lds[wave][e0 + 1] = a01;
    if (act30) {
        lds[wave][128 + e0] = a10;
        lds[wave][129 + e0] = a11;
    }
    __syncthreads();
    float u = (lane < 47)
                  ? 0.25f * (lds[wave][lane] + lds[wave][47 + lane] +
                             lds[wave][94 + lane] + lds[wave][141 + lane])
                  : -__builtin_inff();
    float mx = u;
#pragma unroll
    for (int o = 32; o > 0; o >>= 1) mx = fmaxf(mx, __shfl_xor(mx, o));
    float ex = (lane < 47) ? __expf(u - mx) : 0.f;
    float sm = ex;
#pragma unroll
    for (int o = 32; o > 0; o >>= 1) sm += __shfl_xor(sm, o);
    if (lane < 47) out[(size_t)n * 47 + lane] = u - mx - logf(sm);
}

// ---------------- launch ----------------

extern "C" void kernel_launch(void* const* d_in, const int* in_sizes, int n_in,
                              void* d_out, int out_size, void* d_ws, size_t ws_size,
                              hipStream_t stream) {
    const float* x = (const float*)d_in[0];
    const int* src = (const int*)d_in[1];
    const int* dst = (const int*)d_in[2];
    const float* W1 = (const float*)d_in[3];
    const float* al1 = (const float*)d_in[4];
    const float* ar1 = (const float*)d_in[5];
    const float* W2 = (const float*)d_in[6];
    const float* al2 = (const float*)d_in[7];
    const float* ar2 = (const float*)d_in[8];
    const float* W3 = (const float*)d_in[9];
    const float* al3 = (const float*)d_in[10];
    const float* ar3 = (const float*)d_in[11];
    float* out = (float*)d_out;

    char* p = (char*)d_ws;
    auto alloc = [&](size_t bytes) {
        char* r = p;
        p += (bytes + 255) & ~(size_t)255;
        return r;
    };
    float* bufA = (float*)alloc((size_t)N_NODES * 128 * 4);
    float* bufC = (float*)alloc((size_t)N_NODES * 128 * 4);
    u16* featb = (u16*)alloc((size_t)N_NODES * 192 * 2);
    float* el = (float*)alloc((size_t)N_NODES * NH * 4);
    float* er = (float*)alloc((size_t)N_NODES * NH * 4);
    float* alpha = (float*)alloc((size_t)N_EDGES * NH * 4);
    int* deg = (int*)alloc((size_t)N_NODES * 4);
    int* offs = (int*)alloc((size_t)(N_NODES + 1) * 4);
    int* cursor = (int*)alloc((size_t)N_NODES * 4);
    int* bsum = (int*)alloc(64 * 4);
    int* csrc = (int*)alloc((size_t)N_EDGES * 4);

    // CSR by dst
    hipMemsetAsync(deg, 0, (size_t)N_NODES * 4, stream);
    k_hist<<<(N_EDGES + 255) / 256, 256, 0, stream>>>(dst, deg);
    k_scan1<<<49, 1024, 0, stream>>>(deg, offs, bsum);
    k_scan2<<<1, 64, 0, stream>>>(bsum, 49);
    k_scan3<<<49, 1024, 0, stream>>>(offs, bsum, cursor);
    k_scatter<<<(N_EDGES + 255) / 256, 256, 0, stream>>>(src, dst, cursor, csrc);

    // layer 1
    gemm_tiled<256, 128, 128, 64, 256, 128><<<(N_NODES + 63) / 64, 256, 0, stream>>>(x, W1, featb);
    attn_dots<32, 128><<<N_NODES / 4, 256, 0, stream>>>(featb, al1, ar1, el, er);
    softmax_alpha<<<N_NODES / 4, 256, 0, stream>>>(el, er, offs, csrc, alpha);
    gat_agg128<<<N_NODES / 4, 256, 0, stream>>>(featb, alpha, offs, csrc, bufA);
    // layer 2
    gemm_tiled<128, 128, 128, 64, 256, 128><<<(N_NODES + 63) / 64, 256, 0, stream>>>(bufA, W2, featb);
    attn_dots<32, 128><<<N_NODES / 4, 256, 0, stream>>>(featb, al2, ar2, el, er);
    softmax_alpha<<<N_NODES / 4, 256, 0, stream>>>(el, er, offs, csrc, alpha);
    gat_agg128<<<N_NODES / 4, 256, 0, stream>>>(featb, alpha, offs, csrc, bufC);
    // layer 3
    gemm_tiled<128, 188, 192, 32, 192, 192><<<(N_NODES + 31) / 32, 192, 0, stream>>>(bufC, W3, featb);
    attn_dots<47, 192><<<N_NODES / 4, 256, 0, stream>>>(featb, al3, ar3, el, er);
    softmax_alpha<<<N_NODES / 4, 256, 0, stream>>>(el, er, offs, csrc, alpha);
    gat_agg_final<<<N_NODES / 4, 256, 0, stream>>>(featb, alpha, offs, csrc, out);
}

// Round 5
// 408.719 us; speedup vs baseline: 1.5428x; 1.2498x over previous
//
#include <hip/hip_runtime.h>
#include <hip/hip_bf16.h>
#include <math.h>
#include <string.h>

#define N_NODES 50000
#define N_EDGES 800000
#define NH 4

typedef unsigned int u32;
typedef unsigned short u16;
typedef __attribute__((ext_vector_type(8))) short bf16x8;   // 8 bf16 in 4 VGPRs
typedef __attribute__((ext_vector_type(4))) float f32x4;

__device__ __forceinline__ u32 pack_bf2(float a, float b) {
    __hip_bfloat162 h2 = __float22bfloat162_rn(make_float2(a, b));
    u32 r;
    memcpy(&r, &h2, 4);
    return r;
}
__device__ __forceinline__ float2 bf2_to_f2(u32 u) {
    return make_float2(__uint_as_float(u << 16), __uint_as_float(u & 0xffff0000u));
}
__device__ __forceinline__ short bf16r(float f) {
    __hip_bfloat16 h = __float2bfloat16(f);
    short s;
    memcpy(&s, &h, 2);
    return s;
}

// ---------------- CSR build ----------------

__global__ void k_hist(const int* __restrict__ dst, int* __restrict__ deg) {
    int i = blockIdx.x * 256 + threadIdx.x;
    if (i < N_EDGES) atomicAdd(&deg[dst[i]], 1);
}

__global__ __launch_bounds__(1024) void k_scan1(const int* __restrict__ deg,
                                                int* __restrict__ offs,
                                                int* __restrict__ bsum) {
    __shared__ int tmp[1024];
    int b = blockIdx.x, t = threadIdx.x;
    int i = b * 1024 + t;
    int v = (i < N_NODES) ? deg[i] : 0;
    tmp[t] = v;
    __syncthreads();
    for (int off = 1; off < 1024; off <<= 1) {
        int add = (t >= off) ? tmp[t - off] : 0;
        __syncthreads();
        tmp[t] += add;
        __syncthreads();
    }
    if (i < N_NODES) offs[i] = tmp[t] - v;
    if (t == 1023) bsum[b] = tmp[t];
}

__global__ void k_scan2(int* __restrict__ bsum, int nb) {
    if (blockIdx.x == 0 && threadIdx.x == 0) {
        int run = 0;
        for (int b = 0; b < nb; ++b) { int v = bsum[b]; bsum[b] = run; run += v; }
    }
}

__global__ __launch_bounds__(1024) void k_scan3(int* __restrict__ offs,
                                                const int* __restrict__ bsum,
                                                int* __restrict__ cursor) {
    int b = blockIdx.x, t = threadIdx.x;
    int i = b * 1024 + t;
    if (i < N_NODES) {
        int o = offs[i] + bsum[b];
        offs[i] = o;
        cursor[i] = o;
    }
    if (b == 0 && t == 0) offs[N_NODES] = N_EDGES;
}

__global__ void k_scatter(const int* __restrict__ src, const int* __restrict__ dst,
                          int* __restrict__ cursor, int* __restrict__ csrc) {
    int i = blockIdx.x * 256 + threadIdx.x;
    if (i < N_EDGES) {
        int p = atomicAdd(&cursor[dst[i]], 1);
        csrc[p] = src[i];
    }
}

// ---------------- W pre-pack into MFMA B-fragment layout ----------------
// Wp[kt][nt][lane][j] = bf16(W[kt*32 + (lane>>4)*8 + j][nt*16 + (lane&15)])
template <int K, int NOUT, int NP>
__global__ void prep_w(const float* __restrict__ W, u16* __restrict__ Wp) {
    constexpr int NT = NP / 16;
    int idx = blockIdx.x * 256 + threadIdx.x;
    int total = (K / 32) * NT * 64 * 8;
    if (idx >= total) return;
    int j = idx & 7;
    int lane = (idx >> 3) & 63;
    int rest = idx >> 9;
    int nt = rest % NT;
    int kt = rest / NT;
    int k = kt * 32 + (lane >> 4) * 8 + j;
    int col = nt * 16 + (lane & 15);
    float v = (col < NOUT) ? W[(size_t)k * NOUT + col] : 0.f;
    Wp[idx] = (u16)bf16r(v);
}

// ---------------- MFMA GEMM: feat(bf16,[N,NP]) = A @ W ----------------
// 256 threads = 4 waves; wave w computes rows [blk*64+w*16, +16) x NP cols.
// No LDS. A-frag: 16B contiguous per lane. B-frag: from prepacked Wp.
template <int K, int NOUT, int NP, bool AF32>
__global__ __launch_bounds__(256) void gemm_mfma(const void* __restrict__ Av,
                                                 const u16* __restrict__ Wp,
                                                 u16* __restrict__ feat) {
    constexpr int NT = NP / 16;
    constexpr int KT = K / 32;
    int w = threadIdx.x >> 6, l = threadIdx.x & 63;
    int tile_m0 = blockIdx.x * 64 + w * 16;
    int rowA = tile_m0 + (l & 15);
    if (rowA >= N_NODES) rowA = N_NODES - 1;   // clamp (results discarded)
    int g = l >> 4;

    f32x4 acc[NT];
#pragma unroll
    for (int nt = 0; nt < NT; ++nt) acc[nt] = (f32x4){0.f, 0.f, 0.f, 0.f};

    for (int kt = 0; kt < KT; ++kt) {
        bf16x8 a;
        if constexpr (AF32) {
            const float* ap = (const float*)Av + (size_t)rowA * K + kt * 32 + g * 8;
            float4 f0 = *reinterpret_cast<const float4*>(ap);
            float4 f1 = *reinterpret_cast<const float4*>(ap + 4);
            a[0] = bf16r(f0.x); a[1] = bf16r(f0.y); a[2] = bf16r(f0.z); a[3] = bf16r(f0.w);
            a[4] = bf16r(f1.x); a[5] = bf16r(f1.y); a[6] = bf16r(f1.z); a[7] = bf16r(f1.w);
        } else {
            a = *reinterpret_cast<const bf16x8*>((const u16*)Av + (size_t)rowA * K + kt * 32 + g * 8);
        }
        const u16* wp = Wp + ((size_t)kt * NT) * 512 + (size_t)l * 8;
#pragma unroll
        for (int nt = 0; nt < NT; ++nt) {
            bf16x8 b = *reinterpret_cast<const bf16x8*>(wp + nt * 512);
            acc[nt] = __builtin_amdgcn_mfma_f32_16x16x32_bf16(a, b, acc[nt], 0, 0, 0);
        }
    }

    int rowD0 = tile_m0 + g * 4;
#pragma unroll
    for (int nt = 0; nt < NT; ++nt) {
        int col = nt * 16 + (l & 15);
        if (NP != NOUT && col >= NOUT) continue;
#pragma unroll
        for (int r = 0; r < 4; ++r) {
            int row = rowD0 + r;
            if (row < N_NODES)
                feat[(size_t)row * NP + col] = (u16)bf16r(acc[nt][r]);
        }
    }
}

// ---------------- attention dots (bf16 feat) ----------------
template <int DH, int STRIDE>
__global__ __launch_bounds__(256) void attn_dots(const u16* __restrict__ feat,
                                                 const float* __restrict__ al,
                                                 const float* __restrict__ ar,
                                                 float* __restrict__ el,
                                                 float* __restrict__ er) {
    int wave = threadIdx.x >> 6, lane = threadIdx.x & 63;
    int n = blockIdx.x * 4 + wave;
    int h = lane >> 4, t = lane & 15;
    const u16* f = feat + (size_t)n * STRIDE + h * DH;
    const float* alh = al + h * DH;
    const float* arh = ar + h * DH;
    float sl = 0.f, sr = 0.f;
#pragma unroll
    for (int d0 = 0; d0 < DH; d0 += 16) {
        int d = d0 + t;
        if (d < DH) {
            float fv = __uint_as_float(((u32)f[d]) << 16);
            sl = fmaf(fv, alh[d], sl);
            sr = fmaf(fv, arh[d], sr);
        }
    }
#pragma unroll
    for (int o = 1; o < 16; o <<= 1) {
        sl += __shfl_xor(sl, o);
        sr += __shfl_xor(sr, o);
    }
    if (t == 0) { el[n * NH + h] = sl; er[n * NH + h] = sr; }
}

// ---------------- per-node segment softmax -> normalized alpha[E][4] ----------------
__device__ __forceinline__ float wred_max(float v) {
#pragma unroll
    for (int o = 32; o > 0; o >>= 1) v = fmaxf(v, __shfl_xor(v, o));
    return v;
}
__device__ __forceinline__ float wred_sum(float v) {
#pragma unroll
    for (int o = 32; o > 0; o >>= 1) v += __shfl_xor(v, o);
    return v;
}

__global__ __launch_bounds__(256) void softmax_alpha(const float* __restrict__ el,
                                                     const float* __restrict__ er,
                                                     const int* __restrict__ offs,
                                                     const int* __restrict__ csrc,
                                                     float* __restrict__ alpha) {
    const float NEG = -__builtin_inff();
    int wave = threadIdx.x >> 6, lane = threadIdx.x & 63;
    int n = blockIdx.x * 4 + wave;
    int i0 = offs[n], i1 = offs[n + 1];
    if (i0 >= i1) return;
    float4 erv = *reinterpret_cast<const float4*>(er + (size_t)n * NH);

    if (i1 - i0 <= 64) {
        int i = i0 + lane;
        bool act = i < i1;
        int src = act ? csrc[i] : 0;
        float4 elv = make_float4(0.f, 0.f, 0.f, 0.f);
        if (act) elv = *reinterpret_cast<const float4*>(el + (size_t)src * NH);
        float e0 = elv.x + erv.x; e0 = e0 >= 0.f ? e0 : 0.2f * e0;
        float e1 = elv.y + erv.y; e1 = e1 >= 0.f ? e1 : 0.2f * e1;
        float e2 = elv.z + erv.z; e2 = e2 >= 0.f ? e2 : 0.2f * e2;
        float e3 = elv.w + erv.w; e3 = e3 >= 0.f ? e3 : 0.2f * e3;
        if (!act) { e0 = NEG; e1 = NEG; e2 = NEG; e3 = NEG; }
        float m0 = wred_max(e0), m1 = wred_max(e1), m2 = wred_max(e2), m3 = wred_max(e3);
        float p0 = act ? __expf(e0 - m0) : 0.f;
        float p1 = act ? __expf(e1 - m1) : 0.f;
        float p2 = act ? __expf(e2 - m2) : 0.f;
        float p3 = act ? __expf(e3 - m3) : 0.f;
        float s0 = wred_sum(p0), s1 = wred_sum(p1), s2 = wred_sum(p2), s3 = wred_sum(p3);
        if (act) {
            float4 a = make_float4(p0 / s0, p1 / s1, p2 / s2, p3 / s3);
            *reinterpret_cast<float4*>(alpha + (size_t)i * NH) = a;
        }
        return;
    }

    float m0 = NEG, m1 = NEG, m2 = NEG, m3 = NEG;
    float s0 = 0.f, s1 = 0.f, s2 = 0.f, s3 = 0.f;
    for (int base = i0; base < i1; base += 64) {
        int i = base + lane;
        bool act = i < i1;
        int src = act ? csrc[i] : 0;
        float4 elv = make_float4(0.f, 0.f, 0.f, 0.f);
        if (act) elv = *reinterpret_cast<const float4*>(el + (size_t)src * NH);
        float e0 = elv.x + erv.x; e0 = e0 >= 0.f ? e0 : 0.2f * e0;
        float e1 = elv.y + erv.y; e1 = e1 >= 0.f ? e1 : 0.2f * e1;
        float e2 = elv.z + erv.z; e2 = e2 >= 0.f ? e2 : 0.2f * e2;
        float e3 = elv.w + erv.w; e3 = e3 >= 0.f ? e3 : 0.2f * e3;
        if (!act) { e0 = NEG; e1 = NEG; e2 = NEG; e3 = NEG; }
        float c0 = wred_max(e0), c1 = wred_max(e1), c2 = wred_max(e2), c3 = wred_max(e3);
        float nm0 = fmaxf(m0, c0), nm1 = fmaxf(m1, c1), nm2 = fmaxf(m2, c2), nm3 = fmaxf(m3, c3);
        float p0 = act ? __expf(e0 - nm0) : 0.f;
        float p1 = act ? __expf(e1 - nm1) : 0.f;
        float p2 = act ? __expf(e2 - nm2) : 0.f;
        float p3 = act ? __expf(e3 - nm3) : 0.f;
        float S0 = wred_sum(p0), S1 = wred_sum(p1), S2 = wred_sum(p2), S3 = wred_sum(p3);
        s0 = s0 * __expf(m0 - nm0) + S0; m0 = nm0;
        s1 = s1 * __expf(m1 - nm1) + S1; m1 = nm1;
        s2 = s2 * __expf(m2 - nm2) + S2; m2 = nm2;
        s3 = s3 * __expf(m3 - nm3) + S3; m3 = nm3;
    }
    float v0 = 1.f / s0, v1 = 1.f / s1, v2 = 1.f / s2, v3 = 1.f / s3;
    for (int base = i0; base < i1; base += 64) {
        int i = base + lane;
        bool act = i < i1;
        int src = act ? csrc[i] : 0;
        float4 elv = make_float4(0.f, 0.f, 0.f, 0.f);
        if (act) elv = *reinterpret_cast<const float4*>(el + (size_t)src * NH);
        float e0 = elv.x + erv.x; e0 = e0 >= 0.f ? e0 : 0.2f * e0;
        float e1 = elv.y + erv.y; e1 = e1 >= 0.f ? e1 : 0.2f * e1;
        float e2 = elv.z + erv.z; e2 = e2 >= 0.f ? e2 : 0.2f * e2;
        float e3 = elv.w + erv.w; e3 = e3 >= 0.f ? e3 : 0.2f * e3;
        if (act) {
            float4 a = make_float4(__expf(e0 - m0) * v0, __expf(e1 - m1) * v1,
                                   __expf(e2 - m2) * v2, __expf(e3 - m3) * v3);
            *reinterpret_cast<float4*>(alpha + (size_t)i * NH) = a;
        }
    }
}

// ---------------- aggregation, layers 1-2 (128 cols, bf16 in, bf16 out) ----------------
__global__ __launch_bounds__(256) void gat_agg128(const u16* __restrict__ feat,
                                                  const float* __restrict__ alpha,
                                                  const int* __restrict__ offs,
                                                  const int* __restrict__ csrc,
                                                  u16* __restrict__ out) {
    int wave = threadIdx.x >> 6;
    int lane = threadIdx.x & 63;
    int n = blockIdx.x * 4 + wave;
    int h = lane >> 4;
    int i0 = offs[n], i1 = offs[n + 1];
    float ax = 0.f, ay = 0.f;
    int i = i0;
    for (; i + 4 <= i1; i += 4) {
        int s0 = csrc[i], s1 = csrc[i + 1], s2 = csrc[i + 2], s3 = csrc[i + 3];
        float a0 = alpha[(size_t)(i + 0) * NH + h];
        float a1 = alpha[(size_t)(i + 1) * NH + h];
        float a2 = alpha[(size_t)(i + 2) * NH + h];
        float a3 = alpha[(size_t)(i + 3) * NH + h];
        u32 u0 = *reinterpret_cast<const u32*>(feat + (size_t)s0 * 128 + 2 * lane);
        u32 u1 = *reinterpret_cast<const u32*>(feat + (size_t)s1 * 128 + 2 * lane);
        u32 u2 = *reinterpret_cast<const u32*>(feat + (size_t)s2 * 128 + 2 * lane);
        u32 u3 = *reinterpret_cast<const u32*>(feat + (size_t)s3 * 128 + 2 * lane);
        float2 v;
        v = bf2_to_f2(u0); ax = fmaf(a0, v.x, ax); ay = fmaf(a0, v.y, ay);
        v = bf2_to_f2(u1); ax = fmaf(a1, v.x, ax); ay = fmaf(a1, v.y, ay);
        v = bf2_to_f2(u2); ax = fmaf(a2, v.x, ax); ay = fmaf(a2, v.y, ay);
        v = bf2_to_f2(u3); ax = fmaf(a3, v.x, ax); ay = fmaf(a3, v.y, ay);
    }
    for (; i < i1; ++i) {
        int s = csrc[i];
        float a = alpha[(size_t)i * NH + h];
        u32 u = *reinterpret_cast<const u32*>(feat + (size_t)s * 128 + 2 * lane);
        float2 v = bf2_to_f2(u);
        ax = fmaf(a, v.x, ax); ay = fmaf(a, v.y, ay);
    }
    float ox = ax > 0.f ? ax : expm1f(ax);
    float oy = ay > 0.f ? ay : expm1f(ay);
    *reinterpret_cast<u32*>(out + (size_t)n * 128 + 2 * lane) = pack_bf2(ox, oy);
}

// ---------------- aggregation, layer 3 (188 cols, stride 192) + mean + log_softmax ----
__global__ __launch_bounds__(256) void gat_agg_final(const u16* __restrict__ feat,
                                                     const float* __restrict__ alpha,
                                                     const int* __restrict__ offs,
                                                     const int* __restrict__ csrc,
                                                     float* __restrict__ out) {
    __shared__ float lds[4][188];
    int wave = threadIdx.x >> 6;
    int lane = threadIdx.x & 63;
    int n = blockIdx.x * 4 + wave;
    int e0 = 2 * lane;
    int h00 = e0 / 47;
    int h01 = (e0 + 1) / 47;
    bool act30 = lane < 30;
    int h10 = act30 ? (128 + e0) / 47 : 0;
    int h11 = act30 ? (129 + e0) / 47 : 0;
    int i0 = offs[n], i1 = offs[n + 1];
    float a00 = 0.f, a01 = 0.f, a10 = 0.f, a11 = 0.f;
    int i = i0;
    for (; i + 2 <= i1; i += 2) {
        int sA = csrc[i], sB = csrc[i + 1];
        const float* apA = alpha + (size_t)i * NH;
        const float* apB = alpha + (size_t)(i + 1) * NH;
        float wA00 = apA[h00], wA01 = apA[h01], wA10 = apA[h10], wA11 = apA[h11];
        float wB00 = apB[h00], wB01 = apB[h01], wB10 = apB[h10], wB11 = apB[h11];
        const u16* rA = feat + (size_t)sA * 192;
        const u16* rB = feat + (size_t)sB * 192;
        u32 uA0 = *reinterpret_cast<const u32*>(rA + e0);
        u32 uB0 = *reinterpret_cast<const u32*>(rB + e0);
        u32 uA1 = act30 ? *reinterpret_cast<const u32*>(rA + 128 + e0) : 0u;
        u32 uB1 = act30 ? *reinterpret_cast<const u32*>(rB + 128 + e0) : 0u;
        float2 v;
        v = bf2_to_f2(uA0); a00 = fmaf(wA00, v.x, a00); a01 = fmaf(wA01, v.y, a01);
        v = bf2_to_f2(uA1); a10 = fmaf(wA10, v.x, a10); a11 = fmaf(wA11, v.y, a11);
        v = bf2_to_f2(uB0); a00 = fmaf(wB00, v.x, a00); a01 = fmaf(wB01, v.y, a01);
        v = bf2_to_f2(uB1); a10 = fmaf(wB10, v.x, a10); a11 = fmaf(wB11, v.y, a11);
    }
    for (; i < i1; ++i) {
        int s = csrc[i];
        const float* ap = alpha + (size_t)i * NH;
        float w00 = ap[h00], w01 = ap[h01], w10 = ap[h10], w11 = ap[h11];
        const u16* r = feat + (size_t)s * 192;
        u32 u0 = *reinterpret_cast<const u32*>(r + e0);
        u32 u1 = act30 ? *reinterpret_cast<const u32*>(r + 128 + e0) : 0u;
        float2 v;
        v = bf2_to_f2(u0); a00 = fmaf(w00, v.x, a00); a01 = fmaf(w01, v.y, a01);
        v = bf2_to_f2(u1); a10 = fmaf(w10, v.x, a10); a11 = fmaf(w11, v.y, a11);
    }
    lds[wave][e0] = a00;
    lds[wave][e0 + 1] = a01;
    if (act30) {
        lds[wave][128 + e0] = a10;
        lds[wave][129 + e0] = a11;
    }
    __syncthreads();
    float u = (lane < 47)
                  ? 0.25f * (lds[wave][lane] + lds[wave][47 + lane] +
                             lds[wave][94 + lane] + lds[wave][141 + lane])
                  : -__builtin_inff();
    float mx = u;
#pragma unroll
    for (int o = 32; o > 0; o >>= 1) mx = fmaxf(mx, __shfl_xor(mx, o));
    float ex = (lane < 47) ? __expf(u - mx) : 0.f;
    float sm = ex;
#pragma unroll
    for (int o = 32; o > 0; o >>= 1) sm += __shfl_xor(sm, o);
    if (lane < 47) out[(size_t)n * 47 + lane] = u - mx - logf(sm);
}

// ---------------- launch ----------------

extern "C" void kernel_launch(void* const* d_in, const int* in_sizes, int n_in,
                              void* d_out, int out_size, void* d_ws, size_t ws_size,
                              hipStream_t stream) {
    const float* x = (const float*)d_in[0];
    const int* src = (const int*)d_in[1];
    const int* dst = (const int*)d_in[2];
    const float* W1 = (const float*)d_in[3];
    const float* al1 = (const float*)d_in[4];
    const float* ar1 = (const float*)d_in[5];
    const float* W2 = (const float*)d_in[6];
    const float* al2 = (const float*)d_in[7];
    const float* ar2 = (const float*)d_in[8];
    const float* W3 = (const float*)d_in[9];
    const float* al3 = (const float*)d_in[10];
    const float* ar3 = (const float*)d_in[11];
    float* out = (float*)d_out;

    char* p = (char*)d_ws;
    auto alloc = [&](size_t bytes) {
        char* r = p;
        p += (bytes + 255) & ~(size_t)255;
        return r;
    };
    u16* bufA = (u16*)alloc((size_t)N_NODES * 128 * 2);
    u16* bufC = (u16*)alloc((size_t)N_NODES * 128 * 2);
    u16* featb = (u16*)alloc((size_t)N_NODES * 192 * 2);
    float* el = (float*)alloc((size_t)N_NODES * NH * 4);
    float* er = (float*)alloc((size_t)N_NODES * NH * 4);
    float* alpha = (float*)alloc((size_t)N_EDGES * NH * 4);
    u16* wp1 = (u16*)alloc((size_t)(256 / 32) * 8 * 512 * 2);
    u16* wp2 = (u16*)alloc((size_t)(128 / 32) * 8 * 512 * 2);
    u16* wp3 = (u16*)alloc((size_t)(128 / 32) * 12 * 512 * 2);
    int* deg = (int*)alloc((size_t)N_NODES * 4);
    int* offs = (int*)alloc((size_t)(N_NODES + 1) * 4);
    int* cursor = (int*)alloc((size_t)N_NODES * 4);
    int* bsum = (int*)alloc(64 * 4);
    int* csrc = (int*)alloc((size_t)N_EDGES * 4);

    // W pre-pack (depends only on inputs; do first)
    prep_w<256, 128, 128><<<(8 * 8 * 512 + 255) / 256, 256, 0, stream>>>(W1, wp1);
    prep_w<128, 128, 128><<<(4 * 8 * 512 + 255) / 256, 256, 0, stream>>>(W2, wp2);
    prep_w<128, 188, 192><<<(4 * 12 * 512 + 255) / 256, 256, 0, stream>>>(W3, wp3);

    // CSR by dst
    hipMemsetAsync(deg, 0, (size_t)N_NODES * 4, stream);
    k_hist<<<(N_EDGES + 255) / 256, 256, 0, stream>>>(dst, deg);
    k_scan1<<<49, 1024, 0, stream>>>(deg, offs, bsum);
    k_scan2<<<1, 64, 0, stream>>>(bsum, 49);
    k_scan3<<<49, 1024, 0, stream>>>(offs, bsum, cursor);
    k_scatter<<<(N_EDGES + 255) / 256, 256, 0, stream>>>(src, dst, cursor, csrc);

    int gemm_grid = (N_NODES + 63) / 64;
    // layer 1
    gemm_mfma<256, 128, 128, true><<<gemm_grid, 256, 0, stream>>>(x, wp1, featb);
    attn_dots<32, 128><<<N_NODES / 4, 256, 0, stream>>>(featb, al1, ar1, el, er);
    softmax_alpha<<<N_NODES / 4, 256, 0, stream>>>(el, er, offs, csrc, alpha);
    gat_agg128<<<N_NODES / 4, 256, 0, stream>>>(featb, alpha, offs, csrc, bufA);
    // layer 2
    gemm_mfma<128, 128, 128, false><<<gemm_grid, 256, 0, stream>>>(bufA, wp2, featb);
    attn_dots<32, 128><<<N_NODES / 4, 256, 0, stream>>>(featb, al2, ar2, el, er);
    softmax_alpha<<<N_NODES / 4, 256, 0, stream>>>(el, er, offs, csrc, alpha);
    gat_agg128<<<N_NODES / 4, 256, 0, stream>>>(featb, alpha, offs, csrc, bufC);
    // layer 3
    gemm_mfma<128, 188, 192, false><<<gemm_grid, 256, 0, stream>>>(bufC, wp3, featb);
    attn_dots<47, 192><<<N_NODES / 4, 256, 0, stream>>>(featb, al3, ar3, el, er);
    softmax_alpha<<<N_NODES / 4, 256, 0, stream>>>(el, er, offs, csrc, alpha);
    gat_agg_final<<<N_NODES / 4, 256, 0, stream>>>(featb, alpha, offs, csrc, out);
}

// Round 6
// 386.200 us; speedup vs baseline: 1.6328x; 1.0583x over previous
//
#include <hip/hip_runtime.h>
#include <hip/hip_bf16.h>
#include <math.h>
#include <string.h>

#define N_NODES 50000
#define N_EDGES 800000
#define NH 4

typedef unsigned int u32;
typedef unsigned short u16;
typedef __attribute__((ext_vector_type(8))) short bf16x8;   // 8 bf16 in 4 VGPRs
typedef __attribute__((ext_vector_type(4))) float f32x4;

__device__ __forceinline__ u32 pack_bf2(float a, float b) {
    __hip_bfloat162 h2 = __float22bfloat162_rn(make_float2(a, b));
    u32 r;
    memcpy(&r, &h2, 4);
    return r;
}
__device__ __forceinline__ float2 bf2_to_f2(u32 u) {
    return make_float2(__uint_as_float(u << 16), __uint_as_float(u & 0xffff0000u));
}
__device__ __forceinline__ short bf16r(float f) {
    __hip_bfloat16 h = __float2bfloat16(f);
    short s;
    memcpy(&s, &h, 2);
    return s;
}

// ---------------- CSR build ----------------

__global__ void k_hist(const int* __restrict__ dst, int* __restrict__ deg) {
    int i = blockIdx.x * 256 + threadIdx.x;
    if (i < N_EDGES) atomicAdd(&deg[dst[i]], 1);
}

__global__ __launch_bounds__(1024) void k_scan1(const int* __restrict__ deg,
                                                int* __restrict__ offs,
                                                int* __restrict__ bsum) {
    __shared__ int tmp[1024];
    int b = blockIdx.x, t = threadIdx.x;
    int i = b * 1024 + t;
    int v = (i < N_NODES) ? deg[i] : 0;
    tmp[t] = v;
    __syncthreads();
    for (int off = 1; off < 1024; off <<= 1) {
        int add = (t >= off) ? tmp[t - off] : 0;
        __syncthreads();
        tmp[t] += add;
        __syncthreads();
    }
    if (i < N_NODES) offs[i] = tmp[t] - v;
    if (t == 1023) bsum[b] = tmp[t];
}

__global__ void k_scan2(int* __restrict__ bsum, int nb) {
    if (blockIdx.x == 0 && threadIdx.x == 0) {
        int run = 0;
        for (int b = 0; b < nb; ++b) { int v = bsum[b]; bsum[b] = run; run += v; }
    }
}

__global__ __launch_bounds__(1024) void k_scan3(int* __restrict__ offs,
                                                const int* __restrict__ bsum,
                                                int* __restrict__ cursor) {
    int b = blockIdx.x, t = threadIdx.x;
    int i = b * 1024 + t;
    if (i < N_NODES) {
        int o = offs[i] + bsum[b];
        offs[i] = o;
        cursor[i] = o;
    }
    if (b == 0 && t == 0) offs[N_NODES] = N_EDGES;
}

__global__ void k_scatter(const int* __restrict__ src, const int* __restrict__ dst,
                          int* __restrict__ cursor, int* __restrict__ csrc) {
    int i = blockIdx.x * 256 + threadIdx.x;
    if (i < N_EDGES) {
        int p = atomicAdd(&cursor[dst[i]], 1);
        csrc[p] = src[i];
    }
}

// ---------------- W pre-pack into MFMA B-fragment layout ----------------
template <int K, int NOUT, int NP>
__global__ void prep_w(const float* __restrict__ W, u16* __restrict__ Wp) {
    constexpr int NT = NP / 16;
    int idx = blockIdx.x * 256 + threadIdx.x;
    int total = (K / 32) * NT * 64 * 8;
    if (idx >= total) return;
    int j = idx & 7;
    int lane = (idx >> 3) & 63;
    int rest = idx >> 9;
    int nt = rest % NT;
    int kt = rest / NT;
    int k = kt * 32 + (lane >> 4) * 8 + j;
    int col = nt * 16 + (lane & 15);
    float v = (col < NOUT) ? W[(size_t)k * NOUT + col] : 0.f;
    Wp[idx] = (u16)bf16r(v);
}

// ---------------- MFMA GEMM: feat(bf16,[N,NP]) = A @ W (+fused attn dots) ----------------
// 256 threads = 4 waves; wave w computes rows [blk*64+w*16, +16) x NP cols.
// DOTS: el/er computed from acc in-register (requires 16-aligned head boundaries, DH%16==0).
template <int K, int NOUT, int NP, bool AF32, bool DOTS>
__global__ __launch_bounds__(256) void gemm_mfma(const void* __restrict__ Av,
                                                 const u16* __restrict__ Wp,
                                                 u16* __restrict__ feat,
                                                 const float* __restrict__ al,
                                                 const float* __restrict__ ar,
                                                 float* __restrict__ el,
                                                 float* __restrict__ er) {
    constexpr int NT = NP / 16;
    constexpr int KT = K / 32;
    int w = threadIdx.x >> 6, l = threadIdx.x & 63;
    int tile_m0 = blockIdx.x * 64 + w * 16;
    int c15 = l & 15;
    int rowA = tile_m0 + c15;
    if (rowA >= N_NODES) rowA = N_NODES - 1;   // clamp (results discarded)
    int g = l >> 4;

    f32x4 acc[NT];
#pragma unroll
    for (int nt = 0; nt < NT; ++nt) acc[nt] = (f32x4){0.f, 0.f, 0.f, 0.f};

    for (int kt = 0; kt < KT; ++kt) {
        bf16x8 a;
        if constexpr (AF32) {
            const float* ap = (const float*)Av + (size_t)rowA * K + kt * 32 + g * 8;
            float4 f0 = *reinterpret_cast<const float4*>(ap);
            float4 f1 = *reinterpret_cast<const float4*>(ap + 4);
            a[0] = bf16r(f0.x); a[1] = bf16r(f0.y); a[2] = bf16r(f0.z); a[3] = bf16r(f0.w);
            a[4] = bf16r(f1.x); a[5] = bf16r(f1.y); a[6] = bf16r(f1.z); a[7] = bf16r(f1.w);
        } else {
            a = *reinterpret_cast<const bf16x8*>((const u16*)Av + (size_t)rowA * K + kt * 32 + g * 8);
        }
        const u16* wp = Wp + ((size_t)kt * NT) * 512 + (size_t)l * 8;
#pragma unroll
        for (int nt = 0; nt < NT; ++nt) {
            bf16x8 b = *reinterpret_cast<const bf16x8*>(wp + nt * 512);
            acc[nt] = __builtin_amdgcn_mfma_f32_16x16x32_bf16(a, b, acc[nt], 0, 0, 0);
        }
    }

    int rowD0 = tile_m0 + g * 4;
#pragma unroll
    for (int nt = 0; nt < NT; ++nt) {
        int col = nt * 16 + c15;
        if (NP != NOUT && col >= NOUT) continue;
#pragma unroll
        for (int r = 0; r < 4; ++r) {
            int row = rowD0 + r;
            if (row < N_NODES)
                feat[(size_t)row * NP + col] = (u16)bf16r(acc[nt][r]);
        }
    }

    if constexpr (DOTS) {
        // el[row][h] = sum_d feat[row, h*DH+d]*al[h][d]; DH = NOUT/NH, 16|DH -> head = nt*16/DH
        float alv[NT], arv[NT];
#pragma unroll
        for (int nt = 0; nt < NT; ++nt) {
            alv[nt] = al[nt * 16 + c15];
            arv[nt] = ar[nt * 16 + c15];
        }
#pragma unroll
        for (int r = 0; r < 4; ++r) {
            float hlv[NH] = {0.f, 0.f, 0.f, 0.f};
            float hrv[NH] = {0.f, 0.f, 0.f, 0.f};
#pragma unroll
            for (int nt = 0; nt < NT; ++nt) {
                constexpr int NTH = NT / NH;        // nt blocks per head
                int h = nt / NTH;                   // compile-time after unroll
                hlv[h] = fmaf(acc[nt][r], alv[nt], hlv[h]);
                hrv[h] = fmaf(acc[nt][r], arv[nt], hrv[h]);
            }
#pragma unroll
            for (int o = 1; o < 16; o <<= 1) {
#pragma unroll
                for (int j = 0; j < NH; ++j) {
                    hlv[j] += __shfl_xor(hlv[j], o);
                    hrv[j] += __shfl_xor(hrv[j], o);
                }
            }
            int row = rowD0 + r;
            if (c15 == 0 && row < N_NODES) {
                *reinterpret_cast<float4*>(el + (size_t)row * NH) =
                    make_float4(hlv[0], hlv[1], hlv[2], hlv[3]);
                *reinterpret_cast<float4*>(er + (size_t)row * NH) =
                    make_float4(hrv[0], hrv[1], hrv[2], hrv[3]);
            }
        }
    }
}

// ---------------- attention dots (layer 3 only: DH=47 not 16-aligned) ----------------
template <int DH, int STRIDE>
__global__ __launch_bounds__(256) void attn_dots(const u16* __restrict__ feat,
                                                 const float* __restrict__ al,
                                                 const float* __restrict__ ar,
                                                 float* __restrict__ el,
                                                 float* __restrict__ er) {
    int wave = threadIdx.x >> 6, lane = threadIdx.x & 63;
    int n = blockIdx.x * 4 + wave;
    int h = lane >> 4, t = lane & 15;
    const u16* f = feat + (size_t)n * STRIDE + h * DH;
    const float* alh = al + h * DH;
    const float* arh = ar + h * DH;
    float sl = 0.f, sr = 0.f;
#pragma unroll
    for (int d0 = 0; d0 < DH; d0 += 16) {
        int d = d0 + t;
        if (d < DH) {
            float fv = __uint_as_float(((u32)f[d]) << 16);
            sl = fmaf(fv, alh[d], sl);
            sr = fmaf(fv, arh[d], sr);
        }
    }
#pragma unroll
    for (int o = 1; o < 16; o <<= 1) {
        sl += __shfl_xor(sl, o);
        sr += __shfl_xor(sr, o);
    }
    if (t == 0) { el[n * NH + h] = sl; er[n * NH + h] = sr; }
}

// ---------------- per-node segment softmax -> normalized alpha[E][4] ----------------
__device__ __forceinline__ float wred_max(float v) {
#pragma unroll
    for (int o = 32; o > 0; o >>= 1) v = fmaxf(v, __shfl_xor(v, o));
    return v;
}
__device__ __forceinline__ float wred_sum(float v) {
#pragma unroll
    for (int o = 32; o > 0; o >>= 1) v += __shfl_xor(v, o);
    return v;
}

__global__ __launch_bounds__(256) void softmax_alpha(const float* __restrict__ el,
                                                     const float* __restrict__ er,
                                                     const int* __restrict__ offs,
                                                     const int* __restrict__ csrc,
                                                     float* __restrict__ alpha) {
    const float NEG = -__builtin_inff();
    int wave = threadIdx.x >> 6, lane = threadIdx.x & 63;
    int n = blockIdx.x * 4 + wave;
    int i0 = offs[n], i1 = offs[n + 1];
    if (i0 >= i1) return;
    float4 erv = *reinterpret_cast<const float4*>(er + (size_t)n * NH);

    if (i1 - i0 <= 64) {
        int i = i0 + lane;
        bool act = i < i1;
        int src = act ? csrc[i] : 0;
        float4 elv = make_float4(0.f, 0.f, 0.f, 0.f);
        if (act) elv = *reinterpret_cast<const float4*>(el + (size_t)src * NH);
        float e0 = elv.x + erv.x; e0 = e0 >= 0.f ? e0 : 0.2f * e0;
        float e1 = elv.y + erv.y; e1 = e1 >= 0.f ? e1 : 0.2f * e1;
        float e2 = elv.z + erv.z; e2 = e2 >= 0.f ? e2 : 0.2f * e2;
        float e3 = elv.w + erv.w; e3 = e3 >= 0.f ? e3 : 0.2f * e3;
        if (!act) { e0 = NEG; e1 = NEG; e2 = NEG; e3 = NEG; }
        float m0 = wred_max(e0), m1 = wred_max(e1), m2 = wred_max(e2), m3 = wred_max(e3);
        float p0 = act ? __expf(e0 - m0) : 0.f;
        float p1 = act ? __expf(e1 - m1) : 0.f;
        float p2 = act ? __expf(e2 - m2) : 0.f;
        float p3 = act ? __expf(e3 - m3) : 0.f;
        float s0 = wred_sum(p0), s1 = wred_sum(p1), s2 = wred_sum(p2), s3 = wred_sum(p3);
        if (act) {
            float4 a = make_float4(p0 / s0, p1 / s1, p2 / s2, p3 / s3);
            *reinterpret_cast<float4*>(alpha + (size_t)i * NH) = a;
        }
        return;
    }

    float m0 = NEG, m1 = NEG, m2 = NEG, m3 = NEG;
    float s0 = 0.f, s1 = 0.f, s2 = 0.f, s3 = 0.f;
    for (int base = i0; base < i1; base += 64) {
        int i = base + lane;
        bool act = i < i1;
        int src = act ? csrc[i] : 0;
        float4 elv = make_float4(0.f, 0.f, 0.f, 0.f);
        if (act) elv = *reinterpret_cast<const float4*>(el + (size_t)src * NH);
        float e0 = elv.x + erv.x; e0 = e0 >= 0.f ? e0 : 0.2f * e0;
        float e1 = elv.y + erv.y; e1 = e1 >= 0.f ? e1 : 0.2f * e1;
        float e2 = elv.z + erv.z; e2 = e2 >= 0.f ? e2 : 0.2f * e2;
        float e3 = elv.w + erv.w; e3 = e3 >= 0.f ? e3 : 0.2f * e3;
        if (!act) { e0 = NEG; e1 = NEG; e2 = NEG; e3 = NEG; }
        float c0 = wred_max(e0), c1 = wred_max(e1), c2 = wred_max(e2), c3 = wred_max(e3);
        float nm0 = fmaxf(m0, c0), nm1 = fmaxf(m1, c1), nm2 = fmaxf(m2, c2), nm3 = fmaxf(m3, c3);
        float p0 = act ? __expf(e0 - nm0) : 0.f;
        float p1 = act ? __expf(e1 - nm1) : 0.f;
        float p2 = act ? __expf(e2 - nm2) : 0.f;
        float p3 = act ? __expf(e3 - nm3) : 0.f;
        float S0 = wred_sum(p0), S1 = wred_sum(p1), S2 = wred_sum(p2), S3 = wred_sum(p3);
        s0 = s0 * __expf(m0 - nm0) + S0; m0 = nm0;
        s1 = s1 * __expf(m1 - nm1) + S1; m1 = nm1;
        s2 = s2 * __expf(m2 - nm2) + S2; m2 = nm2;
        s3 = s3 * __expf(m3 - nm3) + S3; m3 = nm3;
    }
    float v0 = 1.f / s0, v1 = 1.f / s1, v2 = 1.f / s2, v3 = 1.f / s3;
    for (int base = i0; base < i1; base += 64) {
        int i = base + lane;
        bool act = i < i1;
        int src = act ? csrc[i] : 0;
        float4 elv = make_float4(0.f, 0.f, 0.f, 0.f);
        if (act) elv = *reinterpret_cast<const float4*>(el + (size_t)src * NH);
        float e0 = elv.x + erv.x; e0 = e0 >= 0.f ? e0 : 0.2f * e0;
        float e1 = elv.y + erv.y; e1 = e1 >= 0.f ? e1 : 0.2f * e1;
        float e2 = elv.z + erv.z; e2 = e2 >= 0.f ? e2 : 0.2f * e2;
        float e3 = elv.w + erv.w; e3 = e3 >= 0.f ? e3 : 0.2f * e3;
        if (act) {
            float4 a = make_float4(__expf(e0 - m0) * v0, __expf(e1 - m1) * v1,
                                   __expf(e2 - m2) * v2, __expf(e3 - m3) * v3);
            *reinterpret_cast<float4*>(alpha + (size_t)i * NH) = a;
        }
    }
}

// ---------------- aggregation, layers 1-2 (128 cols, bf16 in, bf16 out) ----------------
__global__ __launch_bounds__(256) void gat_agg128(const u16* __restrict__ feat,
                                                  const float* __restrict__ alpha,
                                                  const int* __restrict__ offs,
                                                  const int* __restrict__ csrc,
                                                  u16* __restrict__ out) {
    int wave = threadIdx.x >> 6;
    int lane = threadIdx.x & 63;
    int n = blockIdx.x * 4 + wave;
    int h = lane >> 4;
    int i0 = offs[n], i1 = offs[n + 1];
    float ax = 0.f, ay = 0.f;
    int i = i0;
    for (; i + 4 <= i1; i += 4) {
        int s0 = csrc[i], s1 = csrc[i + 1], s2 = csrc[i + 2], s3 = csrc[i + 3];
        float a0 = alpha[(size_t)(i + 0) * NH + h];
        float a1 = alpha[(size_t)(i + 1) * NH + h];
        float a2 = alpha[(size_t)(i + 2) * NH + h];
        float a3 = alpha[(size_t)(i + 3) * NH + h];
        u32 u0 = *reinterpret_cast<const u32*>(feat + (size_t)s0 * 128 + 2 * lane);
        u32 u1 = *reinterpret_cast<const u32*>(feat + (size_t)s1 * 128 + 2 * lane);
        u32 u2 = *reinterpret_cast<const u32*>(feat + (size_t)s2 * 128 + 2 * lane);
        u32 u3 = *reinterpret_cast<const u32*>(feat + (size_t)s3 * 128 + 2 * lane);
        float2 v;
        v = bf2_to_f2(u0); ax = fmaf(a0, v.x, ax); ay = fmaf(a0, v.y, ay);
        v = bf2_to_f2(u1); ax = fmaf(a1, v.x, ax); ay = fmaf(a1, v.y, ay);
        v = bf2_to_f2(u2); ax = fmaf(a2, v.x, ax); ay = fmaf(a2, v.y, ay);
        v = bf2_to_f2(u3); ax = fmaf(a3, v.x, ax); ay = fmaf(a3, v.y, ay);
    }
    for (; i < i1; ++i) {
        int s = csrc[i];
        float a = alpha[(size_t)i * NH + h];
        u32 u = *reinterpret_cast<const u32*>(feat + (size_t)s * 128 + 2 * lane);
        float2 v = bf2_to_f2(u);
        ax = fmaf(a, v.x, ax); ay = fmaf(a, v.y, ay);
    }
    float ox = ax > 0.f ? ax : expm1f(ax);
    float oy = ay > 0.f ? ay : expm1f(ay);
    *reinterpret_cast<u32*>(out + (size_t)n * 128 + 2 * lane) = pack_bf2(ox, oy);
}

// ---------------- aggregation, layer 3 (188 cols, stride 192) + mean + log_softmax ----
__global__ __launch_bounds__(256) void gat_agg_final(const u16* __restrict__ feat,
                                                     const float* __restrict__ alpha,
                                                     const int* __restrict__ offs,
                                                     const int* __restrict__ csrc,
                                                     float* __restrict__ out) {
    __shared__ float lds[4][188];
    int wave = threadIdx.x >> 6;
    int lane = threadIdx.x & 63;
    int n = blockIdx.x * 4 + wave;
    int e0 = 2 * lane;
    // per-lane head selectors (constants): h00,h01 in {0,1,2}; h10,h11 in {2,3}
    int h00 = e0 / 47;
    int h01 = (e0 + 1) / 47;
    bool act30 = lane < 30;
    int h10 = act30 ? (128 + e0) / 47 : 2;
    int h11 = act30 ? (129 + e0) / 47 : 2;
    int i0 = offs[n], i1 = offs[n + 1];
    float a00 = 0.f, a01 = 0.f, a10 = 0.f, a11 = 0.f;

    auto selLo = [](float4 av, int h) { return h == 0 ? av.x : (h == 1 ? av.y : av.z); };
    auto selHi = [](float4 av, int h) { return h == 2 ? av.z : av.w; };

    int i = i0;
    // 4-deep pipeline: 4 alpha float4 + 8-12 feat u32 loads in flight
    for (; i + 4 <= i1; i += 4) {
        int sA = csrc[i], sB = csrc[i + 1], sC = csrc[i + 2], sD = csrc[i + 3];
        float4 avA = *reinterpret_cast<const float4*>(alpha + (size_t)(i + 0) * NH);
        float4 avB = *reinterpret_cast<const float4*>(alpha + (size_t)(i + 1) * NH);
        float4 avC = *reinterpret_cast<const float4*>(alpha + (size_t)(i + 2) * NH);
        float4 avD = *reinterpret_cast<const float4*>(alpha + (size_t)(i + 3) * NH);
        const u16* rA = feat + (size_t)sA * 192;
        const u16* rB = feat + (size_t)sB * 192;
        const u16* rC = feat + (size_t)sC * 192;
        const u16* rD = feat + (size_t)sD * 192;
        u32 uA0 = *reinterpret_cast<const u32*>(rA + e0);
        u32 uB0 = *reinterpret_cast<const u32*>(rB + e0);
        u32 uC0 = *reinterpret_cast<const u32*>(rC + e0);
        u32 uD0 = *reinterpret_cast<const u32*>(rD + e0);
        u32 uA1 = act30 ? *reinterpret_cast<const u32*>(rA + 128 + e0) : 0u;
        u32 uB1 = act30 ? *reinterpret_cast<const u32*>(rB + 128 + e0) : 0u;
        u32 uC1 = act30 ? *reinterpret_cast<const u32*>(rC + 128 + e0) : 0u;
        u32 uD1 = act30 ? *reinterpret_cast<const u32*>(rD + 128 + e0) : 0u;
        float2 v;
        v = bf2_to_f2(uA0); a00 = fmaf(selLo(avA, h00), v.x, a00); a01 = fmaf(selLo(avA, h01), v.y, a01);
        v = bf2_to_f2(uA1); a10 = fmaf(selHi(avA, h10), v.x, a10); a11 = fmaf(selHi(avA, h11), v.y, a11);
        v = bf2_to_f2(uB0); a00 = fmaf(selLo(avB, h00), v.x, a00); a01 = fmaf(selLo(avB, h01), v.y, a01);
        v = bf2_to_f2(uB1); a10 = fmaf(selHi(avB, h10), v.x, a10); a11 = fmaf(selHi(avB, h11), v.y, a11);
        v = bf2_to_f2(uC0); a00 = fmaf(selLo(avC, h00), v.x, a00); a01 = fmaf(selLo(avC, h01), v.y, a01);
        v = bf2_to_f2(uC1); a10 = fmaf(selHi(avC, h10), v.x, a10); a11 = fmaf(selHi(avC, h11), v.y, a11);
        v = bf2_to_f2(uD0); a00 = fmaf(selLo(avD, h00), v.x, a00); a01 = fmaf(selLo(avD, h01), v.y, a01);
        v = bf2_to_f2(uD1); a10 = fmaf(selHi(avD, h10), v.x, a10); a11 = fmaf(selHi(avD, h11), v.y, a11);
    }
    for (; i < i1; ++i) {
        int s = csrc[i];
        float4 av = *reinterpret_cast<const float4*>(alpha + (size_t)i * NH);
        const u16* r = feat + (size_t)s * 192;
        u32 u0 = *reinterpret_cast<const u32*>(r + e0);
        u32 u1 = act30 ? *reinterpret_cast<const u32*>(r + 128 + e0) : 0u;
        float2 v;
        v = bf2_to_f2(u0); a00 = fmaf(selLo(av, h00), v.x, a00); a01 = fmaf(selLo(av, h01), v.y, a01);
        v = bf2_to_f2(u1); a10 = fmaf(selHi(av, h10), v.x, a10); a11 = fmaf(selHi(av, h11), v.y, a11);
    }
    lds[wave][e0] = a00;
    lds[wave][e0 + 1] = a01;
    if (act30) {
        lds[wave][128 + e0] = a10;
        lds[wave][129 + e0] = a11;
    }
    __syncthreads();
    float u = (lane < 47)
                  ? 0.25f * (lds[wave][lane] + lds[wave][47 + lane] +
                             lds[wave][94 + lane] + lds[wave][141 + lane])
                  : -__builtin_inff();
    float mx = u;
#pragma unroll
    for (int o = 32; o > 0; o >>= 1) mx = fmaxf(mx, __shfl_xor(mx, o));
    float ex = (lane < 47) ? __expf(u - mx) : 0.f;
    float sm = ex;
#pragma unroll
    for (int o = 32; o > 0; o >>= 1) sm += __shfl_xor(sm, o);
    if (lane < 47) out[(size_t)n * 47 + lane] = u - mx - logf(sm);
}

// ---------------- launch ----------------

extern "C" void kernel_launch(void* const* d_in, const int* in_sizes, int n_in,
                              void* d_out, int out_size, void* d_ws, size_t ws_size,
                              hipStream_t stream) {
    const float* x = (const float*)d_in[0];
    const int* src = (const int*)d_in[1];
    const int* dst = (const int*)d_in[2];
    const float* W1 = (const float*)d_in[3];
    const float* al1 = (const float*)d_in[4];
    const float* ar1 = (const float*)d_in[5];
    const float* W2 = (const float*)d_in[6];
    const float* al2 = (const float*)d_in[7];
    const float* ar2 = (const float*)d_in[8];
    const float* W3 = (const float*)d_in[9];
    const float* al3 = (const float*)d_in[10];
    const float* ar3 = (const float*)d_in[11];
    float* out = (float*)d_out;

    char* p = (char*)d_ws;
    auto alloc = [&](size_t bytes) {
        char* r = p;
        p += (bytes + 255) & ~(size_t)255;
        return r;
    };
    u16* bufA = (u16*)alloc((size_t)N_NODES * 128 * 2);
    u16* bufC = (u16*)alloc((size_t)N_NODES * 128 * 2);
    u16* featb = (u16*)alloc((size_t)N_NODES * 192 * 2);
    float* el = (float*)alloc((size_t)N_NODES * NH * 4);
    float* er = (float*)alloc((size_t)N_NODES * NH * 4);
    float* alpha = (float*)alloc((size_t)N_EDGES * NH * 4);
    u16* wp1 = (u16*)alloc((size_t)(256 / 32) * 8 * 512 * 2);
    u16* wp2 = (u16*)alloc((size_t)(128 / 32) * 8 * 512 * 2);
    u16* wp3 = (u16*)alloc((size_t)(128 / 32) * 12 * 512 * 2);
    int* deg = (int*)alloc((size_t)N_NODES * 4);
    int* offs = (int*)alloc((size_t)(N_NODES + 1) * 4);
    int* cursor = (int*)alloc((size_t)N_NODES * 4);
    int* bsum = (int*)alloc(64 * 4);
    int* csrc = (int*)alloc((size_t)N_EDGES * 4);

    // W pre-pack
    prep_w<256, 128, 128><<<(8 * 8 * 512 + 255) / 256, 256, 0, stream>>>(W1, wp1);
    prep_w<128, 128, 128><<<(4 * 8 * 512 + 255) / 256, 256, 0, stream>>>(W2, wp2);
    prep_w<128, 188, 192><<<(4 * 12 * 512 + 255) / 256, 256, 0, stream>>>(W3, wp3);

    // CSR by dst
    hipMemsetAsync(deg, 0, (size_t)N_NODES * 4, stream);
    k_hist<<<(N_EDGES + 255) / 256, 256, 0, stream>>>(dst, deg);
    k_scan1<<<49, 1024, 0, stream>>>(deg, offs, bsum);
    k_scan2<<<1, 64, 0, stream>>>(bsum, 49);
    k_scan3<<<49, 1024, 0, stream>>>(offs, bsum, cursor);
    k_scatter<<<(N_EDGES + 255) / 256, 256, 0, stream>>>(src, dst, cursor, csrc);

    int gemm_grid = (N_NODES + 63) / 64;
    // layer 1 (dots fused)
    gemm_mfma<256, 128, 128, true, true><<<gemm_grid, 256, 0, stream>>>(x, wp1, featb, al1, ar1, el, er);
    softmax_alpha<<<N_NODES / 4, 256, 0, stream>>>(el, er, offs, csrc, alpha);
    gat_agg128<<<N_NODES / 4, 256, 0, stream>>>(featb, alpha, offs, csrc, bufA);
    // layer 2 (dots fused)
    gemm_mfma<128, 128, 128, false, true><<<gemm_grid, 256, 0, stream>>>(bufA, wp2, featb, al2, ar2, el, er);
    softmax_alpha<<<N_NODES / 4, 256, 0, stream>>>(el, er, offs, csrc, alpha);
    gat_agg128<<<N_NODES / 4, 256, 0, stream>>>(featb, alpha, offs, csrc, bufC);
    // layer 3 (dots separate: DH=47 not 16-aligned)
    gemm_mfma<128, 188, 192, false, false><<<gemm_grid, 256, 0, stream>>>(bufC, wp3, featb, nullptr, nullptr, nullptr, nullptr);
    attn_dots<47, 192><<<N_NODES / 4, 256, 0, stream>>>(featb, al3, ar3, el, er);
    softmax_alpha<<<N_NODES / 4, 256, 0, stream>>>(el, er, offs, csrc, alpha);
    gat_agg_final<<<N_NODES / 4, 256, 0, stream>>>(featb, alpha, offs, csrc, out);
}